// Round 11
// baseline (413.539 us; speedup 1.0000x reference)
//
#include <hip/hip_runtime.h>
#include <hip/hip_bf16.h>
#include <math.h>

typedef __attribute__((ext_vector_type(8))) __bf16 v8bf;
typedef __attribute__((ext_vector_type(4))) float v4f;

__device__ __forceinline__ unsigned short f2bf(float f) {
  union { float f; unsigned int u; } a; a.f = f;
  unsigned int r = a.u + 0x7fffu + ((a.u >> 16) & 1u);
  return (unsigned short)(r >> 16);
}
__device__ __forceinline__ unsigned short f2bf_trunc(float f) {
  union { float f; unsigned int u; } a; a.f = f;
  return (unsigned short)(a.u >> 16);
}
__device__ __forceinline__ float bf2f(unsigned short u) {
  union { unsigned int i; float f; } a; a.i = ((unsigned int)u) << 16; return a.f;
}
__device__ __forceinline__ float sigm(float x) { return 1.0f / (1.0f + __expf(-x)); }

__device__ __forceinline__ void async16(const void* g, void* l) {
  __builtin_amdgcn_global_load_lds(
      (const __attribute__((address_space(1))) unsigned int*)g,
      (__attribute__((address_space(3))) unsigned int*)l, 16, 0, 0);
}

// ---------- GN(pre)+pos -> HSB bf16 token-major; fused GN(norm) stats ----------
__global__ __launch_bounds__(256) void gn_pre_kernel(
    const float* __restrict__ x, const float* __restrict__ g, const float* __restrict__ be,
    const float* __restrict__ pos, unsigned short* __restrict__ hsb, float* __restrict__ stats) {
  __shared__ float L[16384];
  __shared__ float rs[4], rs2[4], mr[2];
  int b = blockIdx.x >> 5, grp = blockIdx.x & 31;
  const float4* base = (const float4*)(x + ((size_t)b*512 + grp*16)*1024);
  float4* L4 = (float4*)L;
  int w = threadIdx.x >> 6;
  float s = 0.f, s2 = 0.f;
  for (int i = threadIdx.x; i < 4096; i += 256) {
    float4 v = base[i];
    L4[i] = v;
    s += v.x + v.y + v.z + v.w;
    s2 += v.x*v.x + v.y*v.y + v.z*v.z + v.w*v.w;
  }
#pragma unroll
  for (int o = 32; o; o >>= 1) { s += __shfl_xor(s, o); s2 += __shfl_xor(s2, o); }
  if ((threadIdx.x & 63) == 0) { rs[w] = s; rs2[w] = s2; }
  __syncthreads();
  if (threadIdx.x == 0) {
    float ts = rs[0]+rs[1]+rs[2]+rs[3], ts2 = rs2[0]+rs2[1]+rs2[2]+rs2[3];
    float mu = ts * (1.0f/16384.0f);
    float var = ts2 * (1.0f/16384.0f) - mu*mu;
    mr[0] = mu; mr[1] = rsqrtf(var + 1e-6f);
  }
  __syncthreads();
  float mu = mr[0], rstd = mr[1];
  const float4* pb = (const float4*)(pos + (size_t)grp*16*1024);
  float ns = 0.f, ns2 = 0.f;
  for (int i = threadIdx.x; i < 4096; i += 256) {
    float4 v = L4[i], p = pb[i];
    int c = grp*16 + (i >> 8);
    float gg = g[c], bb = be[c];
    float4 o;
    o.x = (v.x - mu)*rstd*gg + bb + p.x;
    o.y = (v.y - mu)*rstd*gg + bb + p.y;
    o.z = (v.z - mu)*rstd*gg + bb + p.z;
    o.w = (v.w - mu)*rstd*gg + bb + p.w;
    L4[i] = o;
    ns += o.x + o.y + o.z + o.w;
    ns2 += o.x*o.x + o.y*o.y + o.z*o.z + o.w*o.w;
  }
#pragma unroll
  for (int o = 32; o; o >>= 1) { ns += __shfl_xor(ns, o); ns2 += __shfl_xor(ns2, o); }
  if ((threadIdx.x & 63) == 0) { rs[w] = ns; rs2[w] = ns2; }
  __syncthreads();
  if (threadIdx.x == 0) {
    float ts = rs[0]+rs[1]+rs[2]+rs[3], ts2 = rs2[0]+rs2[1]+rs2[2]+rs2[3];
    float nmu = ts * (1.0f/16384.0f);
    float nvar = ts2 * (1.0f/16384.0f) - nmu*nmu;
    stats[(b*32+grp)*2] = nmu; stats[(b*32+grp)*2+1] = rsqrtf(nvar + 1e-6f);
  }
#pragma unroll
  for (int j = 0; j < 4; ++j) {
    int sI = threadIdx.x + j*256;
    unsigned int wd[8];
#pragma unroll
    for (int c = 0; c < 8; ++c) {
      unsigned int lo = f2bf(L[(2*c)*1024 + sI]);
      unsigned int hi = f2bf(L[(2*c+1)*1024 + sI]);
      wd[c] = lo | (hi << 16);
    }
    size_t oo = (size_t)(b*1024 + sI)*512 + grp*16;
    *(uint4*)(hsb + oo)     = make_uint4(wd[0], wd[1], wd[2], wd[3]);
    *(uint4*)(hsb + oo + 8) = make_uint4(wd[4], wd[5], wd[6], wd[7]);
  }
}

// ---------- im2col ----------
__global__ __launch_bounds__(256) void im2col_kernel(
    const unsigned short* __restrict__ a1, unsigned short* __restrict__ im2) {
  int row0 = blockIdx.x * 8;
#pragma unroll
  for (int it = 0; it < 3; ++it) {
    int cc = it*256 + threadIdx.x;
    if (cc >= 576) break;
    int rl = cc / 72, rr = cc - rl*72;
    int tap = rr >> 3, ch8 = rr & 7;
    int row = row0 + rl;
    int bb = row >> 10, s = row & 1023;
    int y = s >> 5, xx0 = s & 31;
    int yy = y + tap/3 - 1, xx = xx0 + tap%3 - 1;
    ushort4 v0 = make_ushort4(0,0,0,0), v1 = make_ushort4(0,0,0,0);
    if ((unsigned)yy < 32u && (unsigned)xx < 32u) {
      const unsigned short* src = a1 + ((size_t)(bb*1024 + yy*32 + xx))*64 + ch8*8;
      v0 = *(const ushort4*)src; v1 = *(const ushort4*)(src + 4);
    }
    unsigned short* dst = im2 + (size_t)row*576 + tap*64 + ch8*8;
    *(ushort4*)dst = v0; *(ushort4*)(dst + 4) = v1;
  }
}

// ---------- gate(conv3 fused) + GN(norm) ----------
__global__ __launch_bounds__(256) void gate_norm_kernel(
    const unsigned short* __restrict__ hsb, const unsigned short* __restrict__ a2,
    const float* __restrict__ w3, const float* __restrict__ b3,
    const float* __restrict__ stats, const float* __restrict__ g,
    const float* __restrict__ be,
    unsigned short* __restrict__ sh, unsigned short* __restrict__ msh) {
  int b = blockIdx.y;
  int s = blockIdx.x * 4 + (threadIdx.x >> 6);
  int oct = threadIdx.x & 63;
  int c0 = oct * 8;
  int grp = c0 >> 4;
  float part = bf2f(a2[((size_t)(b*1024) + s)*64 + oct]) * w3[oct];
#pragma unroll
  for (int o = 32; o; o >>= 1) part += __shfl_xor(part, o);
  float wgt = sigm(part + b3[0]);
  float mu = stats[(b*32 + grp)*2], rstd = stats[(b*32 + grp)*2 + 1];
  size_t o = (size_t)(b*1024 + s)*512 + c0;
  ushort4 u0 = *(const ushort4*)(hsb + o), u1 = *(const ushort4*)(hsb + o + 4);
  unsigned short uu[8] = {u0.x,u0.y,u0.z,u0.w,u1.x,u1.y,u1.z,u1.w};
  unsigned short so[8], mo[8];
#pragma unroll
  for (int j = 0; j < 8; ++j) {
    float v = bf2f(uu[j]);
    so[j] = f2bf((v - mu)*rstd*g[c0+j] + be[c0+j]);
    mo[j] = f2bf(v * wgt);
  }
  *(ushort4*)(sh + o)     = make_ushort4(so[0], so[1], so[2], so[3]);
  *(ushort4*)(sh + o + 4) = make_ushort4(so[4], so[5], so[6], so[7]);
  *(ushort4*)(msh + o)     = make_ushort4(mo[0], mo[1], mo[2], mo[3]);
  *(ushort4*)(msh + o + 4) = make_ushort4(mo[4], mo[5], mo[6], mo[7]);
}

// ---------- weight conversions ----------
struct WCvt { const float* src; int dstOff; int n; float scale; };
struct WCvtArgs { WCvt w[15]; };
__global__ __launch_bounds__(256) void wconvert_kernel(WCvtArgs a, unsigned short* __restrict__ dst) {
  WCvt e = a.w[blockIdx.y];
  int i = blockIdx.x * 256 + threadIdx.x;
  if (i >= e.n) return;
  if (blockIdx.y == 13) {
    int oc = i / 576, r = i - oc*576;
    int tap = r >> 6, ic = r & 63;
    dst[e.dstOff + i] = f2bf(e.src[(oc*64 + ic)*9 + tap]);
  } else if (blockIdx.y == 14) {
    dst[e.dstOff + i] = f2bf(e.src[(i & 511)*512 + (i >> 9)]);
  } else {
    dst[e.dstOff + i] = f2bf(e.src[i] * e.scale);
  }
}

__global__ __launch_bounds__(256) void bias_fold_kernel(
    const float* __restrict__ ow, const float* __restrict__ b2,
    const float* __restrict__ ob, float* __restrict__ bc) {
  int n = blockIdx.x * 256 + threadIdx.x;
  float s = ob[n];
  const float* r = ow + (size_t)n * 512;
#pragma unroll 8
  for (int j = 0; j < 512; ++j) s += r[j] * b2[j];
  bc[n] = s;
}

// ---------- merged V transposes ----------
__global__ __launch_bounds__(256) void transpose2_kernel(
    const unsigned short* __restrict__ qkvm,
    unsigned short* __restrict__ vtb, unsigned short* __restrict__ vmt) {
  __shared__ unsigned short t[64][65];
  int s0 = blockIdx.x * 64, c0 = blockIdx.y * 64;
  int z = blockIdx.z, b = z & 7;
  const unsigned short* in = qkvm + (z >= 8 ? 2048 : 1024);
  unsigned short* out = (z >= 8) ? vmt : vtb;
  int tx = threadIdx.x & 63, ty = threadIdx.x >> 6;
#pragma unroll
  for (int i = 0; i < 16; ++i) {
    int s = ty + i*4;
    t[s][tx] = in[((size_t)(b*1024 + s0 + s))*2560 + c0 + tx];
  }
  __syncthreads();
#pragma unroll
  for (int i = 0; i < 16; ++i) {
    int c = ty + i*4;
    out[((size_t)b*512 + c0 + c)*1024 + s0 + tx] = t[tx][c];
  }
}

// ---------- tiled GEMM: BK=64, swizzled LDS, XCD-aware tile mapping ----------
struct GemmDesc {
  const unsigned short* A; const unsigned short* B; void* out; const float* bias;
  int M, N, K, lda, ldb, ldo, epi;
  long long Ay, Az, By, Bz, Oy, Oz;
};

template<int BM, int BN>
__global__ __launch_bounds__(256) void gemm_tile_kernel(GemmDesc d) {
  constexpr int WGM = (BN >= 128) ? 2 : 4;
  constexpr int WGN = 4 / WGM;
  constexpr int MT = BM / (16 * WGM);
  constexpr int NT = BN / (16 * WGN);
  constexpr int AIT = (BM * 8) / 256;
  constexpr int BIT = (BN * 8) / 256;
  __shared__ __align__(16) unsigned short As[BM * 64];
  __shared__ __align__(16) unsigned short Bs[BN * 64];

  int ntx = d.N / BN, mtx = d.M / BM;
  int bmt, bnt;
  if ((mtx & 7) == 0) {
    int xcd = blockIdx.x & 7, j = blockIdx.x >> 3;
    int mpx = mtx >> 3;
    bmt = xcd * mpx + (j % mpx);
    bnt = j / mpx;
  } else {
    bmt = blockIdx.x / ntx; bnt = blockIdx.x % ntx;
  }
  int bm0 = bmt * BM, bn0 = bnt * BN;
  const unsigned short* A = d.A + (long long)blockIdx.y * d.Ay
      + (long long)blockIdx.z * d.Az + (size_t)bm0 * d.lda;
  const unsigned short* B = d.B + (long long)blockIdx.y * d.By
      + (long long)blockIdx.z * d.Bz + (size_t)bn0 * d.ldb;
  int tid = threadIdx.x, lane = tid & 63, w = tid >> 6;
  int wm = (WGN == 2) ? (w >> 1) : w;
  int wn = (WGN == 2) ? (w & 1) : 0;
  int ln = lane & 15, qd = lane >> 4;

  v4f acc[MT][NT];
#pragma unroll
  for (int i = 0; i < MT; ++i)
#pragma unroll
    for (int j = 0; j < NT; ++j) acc[i][j] = (v4f){0.f, 0.f, 0.f, 0.f};

  int nks = d.K >> 6;
  for (int ks = 0; ks < nks; ++ks) {
    int kof = ks * 64;
#pragma unroll
    for (int it = 0; it < AIT; ++it) {
      int c = it * 256 + tid;
      int row = c >> 3, ch = c & 7;
      async16(A + (size_t)row * d.lda + ((ch ^ (row & 7)) << 3) + kof, As + c * 8);
    }
#pragma unroll
    for (int it = 0; it < BIT; ++it) {
      int c = it * 256 + tid;
      int row = c >> 3, ch = c & 7;
      async16(B + (size_t)row * d.ldb + ((ch ^ (row & 7)) << 3) + kof, Bs + c * 8);
    }
    __syncthreads();
#pragma unroll
    for (int k2 = 0; k2 < 2; ++k2) {
      v8bf af[MT], bfr[NT];
#pragma unroll
      for (int i = 0; i < MT; ++i) {
        int row = wm * MT * 16 + i * 16 + ln;
        af[i] = *(const v8bf*)(As + row * 64 + (((k2*4 + qd) ^ (ln & 7)) << 3));
      }
#pragma unroll
      for (int j = 0; j < NT; ++j) {
        int row = wn * NT * 16 + j * 16 + ln;
        bfr[j] = *(const v8bf*)(Bs + row * 64 + (((k2*4 + qd) ^ (ln & 7)) << 3));
      }
#pragma unroll
      for (int i = 0; i < MT; ++i)
#pragma unroll
        for (int j = 0; j < NT; ++j)
          acc[i][j] = __builtin_amdgcn_mfma_f32_16x16x32_bf16(af[i], bfr[j], acc[i][j], 0, 0, 0);
    }
    __syncthreads();
  }

  size_t obase = (size_t)((long long)blockIdx.y * d.Oy + (long long)blockIdx.z * d.Oz);
#pragma unroll
  for (int i = 0; i < MT; ++i) {
#pragma unroll
    for (int j = 0; j < NT; ++j) {
      int col = bn0 + wn * NT * 16 + j * 16 + ln;
      float bia = d.bias ? d.bias[col] : 0.0f;
#pragma unroll
      for (int r = 0; r < 4; ++r) {
        int row = bm0 + wm * MT * 16 + i * 16 + qd * 4 + r;
        float v = acc[i][j][r] + bia;
        if (d.epi == 2) v = v * sigm(v);
        size_t oi = obase + (size_t)row * d.ldo + col;
        if (d.epi == 0) ((float*)d.out)[oi] = v;
        else ((unsigned short*)d.out)[oi] = f2bf(v);
      }
    }
  }
}

// ---------- flash attention, std MHSA: 512 thr, 32 q-rows/wave ----------
__global__ __launch_bounds__(512) void flash_attn_kernel(
    const unsigned short* __restrict__ QKVM, const unsigned short* __restrict__ VTB,
    unsigned short* __restrict__ out) {
  __shared__ __align__(16) unsigned short Ks[128*64];
  __shared__ __align__(16) unsigned short Vts[64*128];
  __shared__ __align__(16) unsigned short Pw[8][32*128];
  int h = blockIdx.x, b = blockIdx.y, qt = blockIdx.z;
  int tid = threadIdx.x, lane = tid & 63, w = tid >> 6;
  int ln = lane & 15, qd = lane >> 4;

  const unsigned short* Qbase = QKVM + ((size_t)(b*1024 + qt*256 + w*32))*2560 + h*64;
  v8bf aq[2][2];
#pragma unroll
  for (int i = 0; i < 2; ++i)
#pragma unroll
    for (int s = 0; s < 2; ++s)
      aq[i][s] = *(const v8bf*)(Qbase + (size_t)(i*16 + ln)*2560 + s*32 + qd*8);

  v4f o_acc[2][4];
  float l_part[2][4];
#pragma unroll
  for (int i = 0; i < 2; ++i) {
#pragma unroll
    for (int dn = 0; dn < 4; ++dn) o_acc[i][dn] = (v4f){0.f,0.f,0.f,0.f};
#pragma unroll
    for (int r = 0; r < 4; ++r) l_part[i][r] = 0.f;
  }

  const unsigned short* Kg = QKVM + 512 + (size_t)(b*1024)*2560 + h*64;
  const unsigned short* Vg = VTB + ((size_t)(b*512) + h*64)*1024;

  for (int kt = 0; kt < 8; ++kt) {
#pragma unroll
    for (int it = 0; it < 2; ++it) {
      int c = it*512 + tid;
      async16(Kg + (size_t)(kt*128 + (c >> 3))*2560 + (((c & 7) ^ ((c >> 3) & 7)) << 3),
              Ks + c*8);
    }
#pragma unroll
    for (int it = 0; it < 2; ++it) {
      int c = it*512 + tid;
      async16(Vg + (size_t)(c >> 4)*1024 + kt*128 + ((((c & 15) ^ ((c >> 4) & 7))) << 3),
              Vts + c*8);
    }
    __syncthreads();

    v4f sc[2][8];
#pragma unroll
    for (int i = 0; i < 2; ++i)
#pragma unroll
      for (int n = 0; n < 8; ++n) sc[i][n] = (v4f){0.f,0.f,0.f,0.f};
#pragma unroll
    for (int n = 0; n < 8; ++n)
#pragma unroll
      for (int s = 0; s < 2; ++s) {
        v8bf kb = *(const v8bf*)(Ks + (n*16 + ln)*64 + (((s*4 + qd) ^ (ln & 7)) << 3));
#pragma unroll
        for (int i = 0; i < 2; ++i)
          sc[i][n] = __builtin_amdgcn_mfma_f32_16x16x32_bf16(aq[i][s], kb, sc[i][n], 0, 0, 0);
      }
#pragma unroll
    for (int i = 0; i < 2; ++i)
#pragma unroll
      for (int r = 0; r < 4; ++r) {
        int row7 = (qd*4 + r) & 7;
        float acc_l = 0.f;
#pragma unroll
        for (int n = 0; n < 8; ++n) {
          float p = exp2f(sc[i][n][r]);
          acc_l += p;
          Pw[w][(i*16 + qd*4 + r)*128 + (((n*2 + (ln >> 3)) ^ row7) << 3) + (ln & 7)] = f2bf_trunc(p);
        }
        l_part[i][r] += acc_l;
      }
    v8bf pf[2][4];
#pragma unroll
    for (int i = 0; i < 2; ++i)
#pragma unroll
      for (int ks2 = 0; ks2 < 4; ++ks2)
        pf[i][ks2] = *(const v8bf*)(&Pw[w][(i*16 + ln)*128 + (((ks2*4 + qd) ^ (ln & 7)) << 3)]);
#pragma unroll
    for (int dn = 0; dn < 4; ++dn)
#pragma unroll
      for (int ks2 = 0; ks2 < 4; ++ks2) {
        v8bf vf = *(const v8bf*)(Vts + (dn*16 + ln)*128 + (((ks2*4 + qd) ^ (ln & 7)) << 3));
#pragma unroll
        for (int i = 0; i < 2; ++i)
          o_acc[i][dn] = __builtin_amdgcn_mfma_f32_16x16x32_bf16(pf[i][ks2], vf, o_acc[i][dn], 0, 0, 0);
      }
    __syncthreads();
  }

  unsigned short* ob = out + ((size_t)(b*1024 + qt*256 + w*32))*1024 + h*64;
#pragma unroll
  for (int i = 0; i < 2; ++i)
#pragma unroll
    for (int r = 0; r < 4; ++r) {
      float l = l_part[i][r];
      l += __shfl_xor(l, 1); l += __shfl_xor(l, 2);
      l += __shfl_xor(l, 4); l += __shfl_xor(l, 8);
      float rinv = 1.0f / l;
#pragma unroll
      for (int dn = 0; dn < 4; ++dn)
        ob[(size_t)(i*16 + qd*4 + r)*1024 + dn*16 + ln] = f2bf(o_acc[i][dn][r] * rinv);
    }
}

// ---------- flash branches: split-K 4, 32-key tiles, 40 KB LDS ----------
// grid (bb=16, kh=4, qt=8), 256 thr = 4 waves x 32 rows -> 128 q-rows/block x 256 keys.
// Writes unnormalized O (bf16) + row-sums l; combine merges 4 slots.
__global__ __launch_bounds__(256) void flash_branch_kernel(
    const unsigned short* __restrict__ QKVM, const unsigned short* __restrict__ QM,
    const unsigned short* __restrict__ VMT, unsigned short* __restrict__ OPH,
    float* __restrict__ LP) {
  __shared__ __align__(16) unsigned short Ks[32*256];    // 16 KB
  __shared__ __align__(16) unsigned short Vts[256*32];   // 16 KB
  __shared__ __align__(16) unsigned short Pw[4][32*32];  // 8 KB
  int bb = blockIdx.x, b = bb >> 1, br = bb & 1;
  int kh = blockIdx.y, qt = blockIdx.z;
  int tid = threadIdx.x, lane = tid & 63, w = tid >> 6;
  int ln = lane & 15, qd = lane >> 4;

  const unsigned short* Qb = QM + ((size_t)(b*1024 + qt*128 + w*32))*512 + br*256;
  v8bf aq[2][8];
#pragma unroll
  for (int i = 0; i < 2; ++i)
#pragma unroll
    for (int s = 0; s < 8; ++s)
      aq[i][s] = *(const v8bf*)(Qb + (size_t)(i*16 + ln)*512 + s*32 + qd*8);

  v4f o_acc[2][16];
  float l_part[2][4];
#pragma unroll
  for (int i = 0; i < 2; ++i) {
#pragma unroll
    for (int dn = 0; dn < 16; ++dn) o_acc[i][dn] = (v4f){0.f,0.f,0.f,0.f};
#pragma unroll
    for (int r = 0; r < 4; ++r) l_part[i][r] = 0.f;
  }

  const unsigned short* Kg = QKVM + 1536 + br*256 + (size_t)(b*1024)*2560;
  const unsigned short* Vg = VMT + ((size_t)(b*512) + br*256)*1024;

  for (int kt = kh*8; kt < kh*8 + 8; ++kt) {   // 8 tiles of 32 keys
#pragma unroll
    for (int it = 0; it < 4; ++it) {   // K tile 32x256 = 1024 chunks (swizzled)
      int c = it*256 + tid;
      int row = c >> 5, ch = c & 31;
      async16(Kg + (size_t)(kt*32 + row)*2560 + ((ch ^ (row & 7)) << 3), Ks + c*8);
    }
#pragma unroll
    for (int it = 0; it < 4; ++it) {   // Vt tile 256x32 = 1024 chunks (no swizzle)
      int c = it*256 + tid;
      int row = c >> 2, ch = c & 3;
      async16(Vg + (size_t)row*1024 + kt*32 + (ch << 3), Vts + c*8);
    }
    __syncthreads();

    // QK^T: kb hoisted across i
    v4f sc[2][2];
#pragma unroll
    for (int i = 0; i < 2; ++i)
#pragma unroll
      for (int n = 0; n < 2; ++n) sc[i][n] = (v4f){0.f,0.f,0.f,0.f};
#pragma unroll
    for (int n = 0; n < 2; ++n)
#pragma unroll
      for (int s = 0; s < 8; ++s) {
        v8bf kb = *(const v8bf*)(Ks + (n*16 + ln)*256 + (((s*4 + qd) ^ (ln & 7)) << 3));
#pragma unroll
        for (int i = 0; i < 2; ++i)
          sc[i][n] = __builtin_amdgcn_mfma_f32_16x16x32_bf16(aq[i][s], kb, sc[i][n], 0, 0, 0);
      }
    // softmax -> Pw (32-key rows: 4 chunks, XOR with row&3 = r)
#pragma unroll
    for (int i = 0; i < 2; ++i)
#pragma unroll
      for (int r = 0; r < 4; ++r) {
        float acc_l = 0.f;
#pragma unroll
        for (int n = 0; n < 2; ++n) {
          float p = exp2f(sc[i][n][r]);
          acc_l += p;
          Pw[w][(i*16 + qd*4 + r)*32 + (((n*2 + (ln >> 3)) ^ r) << 3) + (ln & 7)] = f2bf_trunc(p);
        }
        l_part[i][r] += acc_l;
      }
    // PV: single MFMA k-step (32 keys); pf chunk = qd ^ (ln&3)
    v8bf pf[2];
#pragma unroll
    for (int i = 0; i < 2; ++i)
      pf[i] = *(const v8bf*)(&Pw[w][(i*16 + ln)*32 + ((qd ^ (ln & 3)) << 3)]);
#pragma unroll
    for (int dn = 0; dn < 16; ++dn) {
      v8bf vf = *(const v8bf*)(Vts + (dn*16 + ln)*32 + (qd << 3));
#pragma unroll
      for (int i = 0; i < 2; ++i)
        o_acc[i][dn] = __builtin_amdgcn_mfma_f32_16x16x32_bf16(pf[i], vf, o_acc[i][dn], 0, 0, 0);
    }
    __syncthreads();
  }

  int slot = (bb*8 + qt)*4 + kh;
  unsigned short* Ob = OPH + (size_t)slot*32768;
  float* Lb = LP + (size_t)slot*128;
#pragma unroll
  for (int i = 0; i < 2; ++i)
#pragma unroll
    for (int r = 0; r < 4; ++r) {
      int row = w*32 + i*16 + qd*4 + r;
      float l = l_part[i][r];
      l += __shfl_xor(l, 1); l += __shfl_xor(l, 2);
      l += __shfl_xor(l, 4); l += __shfl_xor(l, 8);
      if (ln == 0) Lb[row] = l;
#pragma unroll
      for (int dn = 0; dn < 16; ++dn)
        Ob[(size_t)row*256 + dn*16 + ln] = f2bf(o_acc[i][dn][r]);
    }
}

// ---------- combine 4 split-K branch slots -> COMB[:, 512:1024] bf16 ----------
__global__ __launch_bounds__(256) void branch_combine_kernel(
    const unsigned short* __restrict__ OPH, const float* __restrict__ LP,
    unsigned short* __restrict__ out) {
  int bb = blockIdx.x, qt = blockIdx.y;
  int b = bb >> 1, br = bb & 1;
  int s0 = (bb*8 + qt)*4;
  int row = threadIdx.x >> 1, cseg = (threadIdx.x & 1) * 128;
  float l = LP[(size_t)s0*128 + row] + LP[(size_t)(s0+1)*128 + row]
          + LP[(size_t)(s0+2)*128 + row] + LP[(size_t)(s0+3)*128 + row];
  float rinv = 1.0f / l;
  unsigned short* ob = out + ((size_t)(b*1024 + qt*128 + row))*1024 + 512 + br*256 + cseg;
#pragma unroll
  for (int j = 0; j < 16; ++j) {
    float acc[8] = {0,0,0,0,0,0,0,0};
#pragma unroll
    for (int k = 0; k < 4; ++k) {
      const unsigned short* p = OPH + (size_t)(s0+k)*32768 + (size_t)row*256 + cseg + j*8;
      uint4 u = *(const uint4*)p;
      unsigned int ww[4] = {u.x, u.y, u.z, u.w};
#pragma unroll
      for (int e = 0; e < 4; ++e) {
        acc[e*2]   += bf2f((unsigned short)(ww[e] & 0xffff));
        acc[e*2+1] += bf2f((unsigned short)(ww[e] >> 16));
      }
    }
    unsigned int wd[4];
#pragma unroll
    for (int e = 0; e < 4; ++e) {
      unsigned int lo = f2bf(acc[e*2] * rinv);
      unsigned int hi = f2bf(acc[e*2+1] * rinv);
      wd[e] = lo | (hi << 16);
    }
    *(uint4*)(ob + j*8) = make_uint4(wd[0], wd[1], wd[2], wd[3]);
  }
}

// ---------- stats over (B,S,C) bf16 per (b,group) ----------
__global__ __launch_bounds__(256) void gn_stats_bf16_kernel(
    const unsigned short* __restrict__ t, float* __restrict__ stats) {
  int b = blockIdx.x >> 5, grp = blockIdx.x & 31;
  float s = 0.f, s2 = 0.f;
#pragma unroll
  for (int j = 0; j < 4; ++j) {
    int sI = threadIdx.x + j*256;
    const unsigned short* p = t + ((size_t)(b*1024 + sI))*512 + grp*16;
    uint4 a = *(const uint4*)p, c2 = *(const uint4*)(p + 8);
    unsigned int ww[8] = {a.x,a.y,a.z,a.w,c2.x,c2.y,c2.z,c2.w};
#pragma unroll
    for (int k = 0; k < 8; ++k) {
      float lo = bf2f((unsigned short)(ww[k] & 0xffff));
      float hi = bf2f((unsigned short)(ww[k] >> 16));
      s += lo + hi; s2 += lo*lo + hi*hi;
    }
  }
#pragma unroll
  for (int o = 32; o; o >>= 1) { s += __shfl_xor(s, o); s2 += __shfl_xor(s2, o); }
  __shared__ float rs[4], rs2[4];
  int w = threadIdx.x >> 6;
  if ((threadIdx.x & 63) == 0) { rs[w] = s; rs2[w] = s2; }
  __syncthreads();
  if (threadIdx.x == 0) {
    float ts = rs[0]+rs[1]+rs[2]+rs[3], ts2 = rs2[0]+rs2[1]+rs2[2]+rs2[3];
    float mu = ts * (1.0f/16384.0f);
    float var = ts2 * (1.0f/16384.0f) - mu*mu;
    stats[(b*32+grp)*2] = mu; stats[(b*32+grp)*2+1] = rsqrtf(var + 1e-6f);
  }
}

// ---------- GN(post) + residual ----------
__global__ __launch_bounds__(256) void final_out_kernel(
    const unsigned short* __restrict__ fin, const float* __restrict__ stats,
    const float* __restrict__ g, const float* __restrict__ be,
    const float* __restrict__ x, float* __restrict__ out) {
  __shared__ float t[64][65];
  int s0 = blockIdx.x * 64, c0 = blockIdx.y * 64, b = blockIdx.z;
  int tx = threadIdx.x & 63, ty = threadIdx.x >> 6;
#pragma unroll
  for (int i = 0; i < 16; ++i) {
    int s = ty + i*4;
    t[s][tx] = bf2f(fin[((size_t)(b*1024 + s0 + s))*512 + c0 + tx]);
  }
  __syncthreads();
#pragma unroll
  for (int i = 0; i < 16; ++i) {
    int c = ty + i*4;
    int cc = c0 + c, grp = cc >> 4;
    float mu = stats[(b*32+grp)*2], rstd = stats[(b*32+grp)*2+1];
    float gg = g[cc], bb = be[cc];
    size_t oi = ((size_t)(b*512 + cc))*1024 + s0 + tx;
    out[oi] = (t[tx][c] - mu)*rstd*gg + bb + x[oi];
  }
}

// =====================================================================
static void launch_gemm128(hipStream_t st, const unsigned short* A, const unsigned short* B,
                           void* out, const float* bias,
                           int M, int N, int K, int lda, int ldb, int ldo, int epi,
                           long long Ay, long long Az, long long By, long long Bz,
                           long long Oy, long long Oz, int gy, int gz) {
  GemmDesc d{A, B, out, bias, M, N, K, lda, ldb, ldo, epi, Ay, Az, By, Bz, Oy, Oz};
  gemm_tile_kernel<128,128><<<dim3((M/128)*(N/128), gy, gz), dim3(256), 0, st>>>(d);
}
static void launch_gemm64(hipStream_t st, const unsigned short* A, const unsigned short* B,
                          void* out, const float* bias,
                          int M, int N, int K, int lda, int ldb, int ldo, int epi) {
  GemmDesc d{A, B, out, bias, M, N, K, lda, ldb, ldo, epi, 0,0,0,0,0,0};
  gemm_tile_kernel<128,64><<<dim3((M/128)*(N/64), 1, 1), dim3(256), 0, st>>>(d);
}

extern "C" void kernel_launch(void* const* d_in, const int* in_sizes, int n_in,
                              void* d_out, int out_size, void* d_ws, size_t ws_size,
                              hipStream_t stream) {
  const float* x      = (const float*)d_in[0];
  const float* pre_g  = (const float*)d_in[1];
  const float* pre_b  = (const float*)d_in[2];
  const float* norm_g = (const float*)d_in[3];
  const float* norm_b = (const float*)d_in[4];
  const float* post_g = (const float*)d_in[5];
  const float* post_b = (const float*)d_in[6];
  const float* pos    = (const float*)d_in[7];
  const float* sa_b1  = (const float*)d_in[9];
  const float* sa_b2  = (const float*)d_in[11];
  const float* sa_w3  = (const float*)d_in[12];
  const float* sa_b3  = (const float*)d_in[13];
  const float* ff_b1  = (const float*)d_in[24];
  const float* ff_b2  = (const float*)d_in[26];
  const float* out_w  = (const float*)d_in[27];
  const float* out_b  = (const float*)d_in[28];
  float* outp = (float*)d_out;

  char* ws = (char*)d_ws;
  size_t off = 0;
  auto alloc = [&](size_t bytes) -> void* {
    void* p = ws + off; off += (bytes + 255) & ~(size_t)255; return p;
  };
  float* STATS = (float*)alloc(4096);
  float* BC    = (float*)alloc(2048);
  unsigned short* HSB  = (unsigned short*)alloc(8388608);
  unsigned short* A1   = (unsigned short*)alloc(1048576);
  unsigned short* IM2  = (unsigned short*)alloc(9437184);
  unsigned short* A2   = (unsigned short*)alloc(1048576);
  unsigned short* SHB  = (unsigned short*)alloc(8388608);
  unsigned short* MSHB = (unsigned short*)alloc(8388608);
  unsigned short* WBF  = (unsigned short*)alloc(6291456);
  unsigned short* WCOMB= (unsigned short*)alloc(524288);
  unsigned short* QKVM = (unsigned short*)alloc(41943040);
  unsigned short* QM   = (unsigned short*)alloc(8388608);
  unsigned short* VTB  = (unsigned short*)alloc(8388608);
  unsigned short* VMT  = (unsigned short*)alloc(8388608);
  unsigned short* COMB = (unsigned short*)alloc(16777216);
  unsigned short* FFMID= (unsigned short*)alloc(8388608);
  unsigned short* FINALB=(unsigned short*)alloc(8388608);
  unsigned short* OPH  = (unsigned short*)alloc(33554432); // 512 slots x 128x256 bf16
  float* LP    = (float*)alloc(262144);                    // 512 slots x 128 f32

  const int OQKVM=0, OQM=1310720, OFF1=1572864, OFF2T=2097152,
            OOW=2359296, OW1=2621440, OW2R=2654208;

  // 1) GN(pre)+pos -> HSB + GN(norm) stats
  gn_pre_kernel<<<dim3(256), dim3(256), 0, stream>>>(x, pre_g, pre_b, pos, HSB, STATS);
  // 2) weights -> bf16 (log2e folded into all attention Q weights)
  {
    WCvtArgs a;
    const float LG2E = 1.4426950408889634f;
    const int   srcIdx[15] = {14,15,16, 18,21,19,22, 17,20, 23,27, 8, 0, 10, 25};
    const int   dofs[15]   = {0, 262144, 524288,
                              786432, 917504, 1048576, 1179648,
                              OQM, OQM+131072,
                              OFF1, OOW, OW1, 0, OW2R, OFF2T};
    const int   ns[15]     = {262144,262144,262144, 131072,131072,131072,131072,
                              131072,131072, 524288,262144, 32768, 0, 36864, 262144};
    const float sc[15]     = {0.125f*LG2E,1.f,1.f, 1.f,1.f,1.f,1.f,
                              0.0625f*LG2E,0.0625f*LG2E, 1.f,1.f, 1.f, 0.f, 1.f, 1.f};
    for (int i = 0; i < 15; ++i) { a.w[i].src = (const float*)d_in[srcIdx[i]]; a.w[i].dstOff = dofs[i]; a.w[i].n = ns[i]; a.w[i].scale = sc[i]; }
    wconvert_kernel<<<dim3(2048, 15), dim3(256), 0, stream>>>(a, WBF);
  }
  // 2b) fold FF2+OW
  {
    GemmDesc d{WBF+OOW, WBF+OFF2T, WCOMB, nullptr, 512, 512, 512, 512, 512, 512, 1, 0,0,0,0,0,0};
    gemm_tile_kernel<128,128><<<dim3(16, 1, 1), dim3(256), 0, stream>>>(d);
  }
  bias_fold_kernel<<<dim3(2), dim3(256), 0, stream>>>(out_w, ff_b2, out_b, BC);
  // 3) spatial gate chain
  launch_gemm64(stream, HSB, WBF+OW1,  A1, sa_b1, 8192, 64, 512, 512, 512, 64, 2);
  im2col_kernel<<<dim3(1024), dim3(256), 0, stream>>>(A1, IM2);
  launch_gemm64(stream, IM2, WBF+OW2R, A2, sa_b2, 8192, 64, 576, 576, 576, 64, 2);
  // 4) gate + norm
  gate_norm_kernel<<<dim3(256, 8), dim3(256), 0, stream>>>(HSB, A2, sa_w3, sa_b3, STATS, norm_g, norm_b, SHB, MSHB);

  // 5) projections
  launch_gemm128(stream, SHB,  WBF+OQKVM, QKVM, nullptr, 8192, 2560, 512, 512, 512, 2560, 1, 0,0,0,0,0,0, 1,1);
  launch_gemm64(stream, MSHB, WBF+OQM,   QM,   nullptr, 8192, 512,  512, 512, 512, 512,  1);

  // 6) V transposes
  transpose2_kernel<<<dim3(16, 8, 16), dim3(256), 0, stream>>>(QKVM, VTB, VMT);

  // 7) std MHSA flash -> COMB[:, 0:512]
  flash_attn_kernel<<<dim3(8, 8, 4), dim3(512), 0, stream>>>(QKVM, VTB, COMB);

  // 8) branch flash split-K 4 (40 KB LDS, 512 blocks) + combine -> COMB[:, 512:]
  flash_branch_kernel<<<dim3(16, 4, 8), dim3(256), 0, stream>>>(QKVM, QM, VMT, OPH, LP);
  branch_combine_kernel<<<dim3(16, 8), dim3(256), 0, stream>>>(OPH, LP, COMB);

  // 9) FF (folded FF2+OW)
  launch_gemm64(stream, COMB,  WBF+OFF1, FFMID,  ff_b1, 8192, 512, 1024, 1024, 1024, 512, 2);
  launch_gemm64(stream, FFMID, WCOMB,    FINALB, BC,    8192, 512, 512,  512,  512,  512, 1);

  // 10) GN(post) + residual
  gn_stats_bf16_kernel<<<dim3(256), dim3(256), 0, stream>>>(FINALB, STATS);
  final_out_kernel<<<dim3(16, 8, 8), dim3(256), 0, stream>>>(FINALB, STATS, post_g, post_b, x, outp);

  (void)in_sizes; (void)n_in; (void)out_size; (void)ws_size;
}

// Round 13
// 386.173 us; speedup vs baseline: 1.0709x; 1.0709x over previous
//
#include <hip/hip_runtime.h>
#include <hip/hip_bf16.h>
#include <math.h>

typedef __attribute__((ext_vector_type(8))) __bf16 v8bf;
typedef __attribute__((ext_vector_type(4))) float v4f;

__device__ __forceinline__ unsigned short f2bf(float f) {
  union { float f; unsigned int u; } a; a.f = f;
  unsigned int r = a.u + 0x7fffu + ((a.u >> 16) & 1u);
  return (unsigned short)(r >> 16);
}
__device__ __forceinline__ unsigned short f2bf_trunc(float f) {
  union { float f; unsigned int u; } a; a.f = f;
  return (unsigned short)(a.u >> 16);
}
__device__ __forceinline__ float bf2f(unsigned short u) {
  union { unsigned int i; float f; } a; a.i = ((unsigned int)u) << 16; return a.f;
}
__device__ __forceinline__ float sigm(float x) { return 1.0f / (1.0f + __expf(-x)); }

__device__ __forceinline__ void async16(const void* g, void* l) {
  __builtin_amdgcn_global_load_lds(
      (const __attribute__((address_space(1))) unsigned int*)g,
      (__attribute__((address_space(3))) unsigned int*)l, 16, 0, 0);
}

// ---------- GN(pre)+pos -> HSB bf16 token-major; fused GN(norm) stats ----------
__global__ __launch_bounds__(256) void gn_pre_kernel(
    const float* __restrict__ x, const float* __restrict__ g, const float* __restrict__ be,
    const float* __restrict__ pos, unsigned short* __restrict__ hsb, float* __restrict__ stats) {
  __shared__ float L[16384];
  __shared__ float rs[4], rs2[4], mr[2];
  int b = blockIdx.x >> 5, grp = blockIdx.x & 31;
  const float4* base = (const float4*)(x + ((size_t)b*512 + grp*16)*1024);
  float4* L4 = (float4*)L;
  int w = threadIdx.x >> 6;
  float s = 0.f, s2 = 0.f;
  for (int i = threadIdx.x; i < 4096; i += 256) {
    float4 v = base[i];
    L4[i] = v;
    s += v.x + v.y + v.z + v.w;
    s2 += v.x*v.x + v.y*v.y + v.z*v.z + v.w*v.w;
  }
#pragma unroll
  for (int o = 32; o; o >>= 1) { s += __shfl_xor(s, o); s2 += __shfl_xor(s2, o); }
  if ((threadIdx.x & 63) == 0) { rs[w] = s; rs2[w] = s2; }
  __syncthreads();
  if (threadIdx.x == 0) {
    float ts = rs[0]+rs[1]+rs[2]+rs[3], ts2 = rs2[0]+rs2[1]+rs2[2]+rs2[3];
    float mu = ts * (1.0f/16384.0f);
    float var = ts2 * (1.0f/16384.0f) - mu*mu;
    mr[0] = mu; mr[1] = rsqrtf(var + 1e-6f);
  }
  __syncthreads();
  float mu = mr[0], rstd = mr[1];
  const float4* pb = (const float4*)(pos + (size_t)grp*16*1024);
  float ns = 0.f, ns2 = 0.f;
  for (int i = threadIdx.x; i < 4096; i += 256) {
    float4 v = L4[i], p = pb[i];
    int c = grp*16 + (i >> 8);
    float gg = g[c], bb = be[c];
    float4 o;
    o.x = (v.x - mu)*rstd*gg + bb + p.x;
    o.y = (v.y - mu)*rstd*gg + bb + p.y;
    o.z = (v.z - mu)*rstd*gg + bb + p.z;
    o.w = (v.w - mu)*rstd*gg + bb + p.w;
    L4[i] = o;
    ns += o.x + o.y + o.z + o.w;
    ns2 += o.x*o.x + o.y*o.y + o.z*o.z + o.w*o.w;
  }
#pragma unroll
  for (int o = 32; o; o >>= 1) { ns += __shfl_xor(ns, o); ns2 += __shfl_xor(ns2, o); }
  if ((threadIdx.x & 63) == 0) { rs[w] = ns; rs2[w] = ns2; }
  __syncthreads();
  if (threadIdx.x == 0) {
    float ts = rs[0]+rs[1]+rs[2]+rs[3], ts2 = rs2[0]+rs2[1]+rs2[2]+rs2[3];
    float nmu = ts * (1.0f/16384.0f);
    float nvar = ts2 * (1.0f/16384.0f) - nmu*nmu;
    stats[(b*32+grp)*2] = nmu; stats[(b*32+grp)*2+1] = rsqrtf(nvar + 1e-6f);
  }
#pragma unroll
  for (int j = 0; j < 4; ++j) {
    int sI = threadIdx.x + j*256;
    unsigned int wd[8];
#pragma unroll
    for (int c = 0; c < 8; ++c) {
      unsigned int lo = f2bf(L[(2*c)*1024 + sI]);
      unsigned int hi = f2bf(L[(2*c+1)*1024 + sI]);
      wd[c] = lo | (hi << 16);
    }
    size_t oo = (size_t)(b*1024 + sI)*512 + grp*16;
    *(uint4*)(hsb + oo)     = make_uint4(wd[0], wd[1], wd[2], wd[3]);
    *(uint4*)(hsb + oo + 8) = make_uint4(wd[4], wd[5], wd[6], wd[7]);
  }
}

// ---------- im2col ----------
__global__ __launch_bounds__(256) void im2col_kernel(
    const unsigned short* __restrict__ a1, unsigned short* __restrict__ im2) {
  int row0 = blockIdx.x * 8;
#pragma unroll
  for (int it = 0; it < 3; ++it) {
    int cc = it*256 + threadIdx.x;
    if (cc >= 576) break;
    int rl = cc / 72, rr = cc - rl*72;
    int tap = rr >> 3, ch8 = rr & 7;
    int row = row0 + rl;
    int bb = row >> 10, s = row & 1023;
    int y = s >> 5, xx0 = s & 31;
    int yy = y + tap/3 - 1, xx = xx0 + tap%3 - 1;
    ushort4 v0 = make_ushort4(0,0,0,0), v1 = make_ushort4(0,0,0,0);
    if ((unsigned)yy < 32u && (unsigned)xx < 32u) {
      const unsigned short* src = a1 + ((size_t)(bb*1024 + yy*32 + xx))*64 + ch8*8;
      v0 = *(const ushort4*)src; v1 = *(const ushort4*)(src + 4);
    }
    unsigned short* dst = im2 + (size_t)row*576 + tap*64 + ch8*8;
    *(ushort4*)dst = v0; *(ushort4*)(dst + 4) = v1;
  }
}

// ---------- gate(conv3 fused) + GN(norm) ----------
__global__ __launch_bounds__(256) void gate_norm_kernel(
    const unsigned short* __restrict__ hsb, const unsigned short* __restrict__ a2,
    const float* __restrict__ w3, const float* __restrict__ b3,
    const float* __restrict__ stats, const float* __restrict__ g,
    const float* __restrict__ be,
    unsigned short* __restrict__ sh, unsigned short* __restrict__ msh) {
  int b = blockIdx.y;
  int s = blockIdx.x * 4 + (threadIdx.x >> 6);
  int oct = threadIdx.x & 63;
  int c0 = oct * 8;
  int grp = c0 >> 4;
  float part = bf2f(a2[((size_t)(b*1024) + s)*64 + oct]) * w3[oct];
#pragma unroll
  for (int o = 32; o; o >>= 1) part += __shfl_xor(part, o);
  float wgt = sigm(part + b3[0]);
  float mu = stats[(b*32 + grp)*2], rstd = stats[(b*32 + grp)*2 + 1];
  size_t o = (size_t)(b*1024 + s)*512 + c0;
  ushort4 u0 = *(const ushort4*)(hsb + o), u1 = *(const ushort4*)(hsb + o + 4);
  unsigned short uu[8] = {u0.x,u0.y,u0.z,u0.w,u1.x,u1.y,u1.z,u1.w};
  unsigned short so[8], mo[8];
#pragma unroll
  for (int j = 0; j < 8; ++j) {
    float v = bf2f(uu[j]);
    so[j] = f2bf((v - mu)*rstd*g[c0+j] + be[c0+j]);
    mo[j] = f2bf(v * wgt);
  }
  *(ushort4*)(sh + o)     = make_ushort4(so[0], so[1], so[2], so[3]);
  *(ushort4*)(sh + o + 4) = make_ushort4(so[4], so[5], so[6], so[7]);
  *(ushort4*)(msh + o)     = make_ushort4(mo[0], mo[1], mo[2], mo[3]);
  *(ushort4*)(msh + o + 4) = make_ushort4(mo[4], mo[5], mo[6], mo[7]);
}

// ---------- weight conversions ----------
struct WCvt { const float* src; int dstOff; int n; float scale; };
struct WCvtArgs { WCvt w[15]; };
__global__ __launch_bounds__(256) void wconvert_kernel(WCvtArgs a, unsigned short* __restrict__ dst) {
  WCvt e = a.w[blockIdx.y];
  int i = blockIdx.x * 256 + threadIdx.x;
  if (i >= e.n) return;
  if (blockIdx.y == 13) {
    int oc = i / 576, r = i - oc*576;
    int tap = r >> 6, ic = r & 63;
    dst[e.dstOff + i] = f2bf(e.src[(oc*64 + ic)*9 + tap]);
  } else if (blockIdx.y == 14) {
    dst[e.dstOff + i] = f2bf(e.src[(i & 511)*512 + (i >> 9)]);
  } else {
    dst[e.dstOff + i] = f2bf(e.src[i] * e.scale);
  }
}

__global__ __launch_bounds__(256) void bias_fold_kernel(
    const float* __restrict__ ow, const float* __restrict__ b2,
    const float* __restrict__ ob, float* __restrict__ bc) {
  int n = blockIdx.x * 256 + threadIdx.x;
  float s = ob[n];
  const float* r = ow + (size_t)n * 512;
#pragma unroll 8
  for (int j = 0; j < 512; ++j) s += r[j] * b2[j];
  bc[n] = s;
}

// ---------- merged V transposes ----------
__global__ __launch_bounds__(256) void transpose2_kernel(
    const unsigned short* __restrict__ qkvm,
    unsigned short* __restrict__ vtb, unsigned short* __restrict__ vmt) {
  __shared__ unsigned short t[64][65];
  int s0 = blockIdx.x * 64, c0 = blockIdx.y * 64;
  int z = blockIdx.z, b = z & 7;
  const unsigned short* in = qkvm + (z >= 8 ? 2048 : 1024);
  unsigned short* out = (z >= 8) ? vmt : vtb;
  int tx = threadIdx.x & 63, ty = threadIdx.x >> 6;
#pragma unroll
  for (int i = 0; i < 16; ++i) {
    int s = ty + i*4;
    t[s][tx] = in[((size_t)(b*1024 + s0 + s))*2560 + c0 + tx];
  }
  __syncthreads();
#pragma unroll
  for (int i = 0; i < 16; ++i) {
    int c = ty + i*4;
    out[((size_t)b*512 + c0 + c)*1024 + s0 + tx] = t[tx][c];
  }
}

// ---------- tiled GEMM: BK=64, swizzled LDS, XCD-aware tile mapping ----------
struct GemmDesc {
  const unsigned short* A; const unsigned short* B; void* out; const float* bias;
  int M, N, K, lda, ldb, ldo, epi;
  long long Ay, Az, By, Bz, Oy, Oz;
};

template<int BM, int BN>
__global__ __launch_bounds__(256) void gemm_tile_kernel(GemmDesc d) {
  constexpr int WGM = (BN >= 128) ? 2 : 4;
  constexpr int WGN = 4 / WGM;
  constexpr int MT = BM / (16 * WGM);
  constexpr int NT = BN / (16 * WGN);
  constexpr int AIT = (BM * 8) / 256;
  constexpr int BIT = (BN * 8) / 256;
  __shared__ __align__(16) unsigned short As[BM * 64];
  __shared__ __align__(16) unsigned short Bs[BN * 64];

  int ntx = d.N / BN, mtx = d.M / BM;
  int bmt, bnt;
  if ((mtx & 7) == 0) {
    int xcd = blockIdx.x & 7, j = blockIdx.x >> 3;
    int mpx = mtx >> 3;
    bmt = xcd * mpx + (j % mpx);
    bnt = j / mpx;
  } else {
    bmt = blockIdx.x / ntx; bnt = blockIdx.x % ntx;
  }
  int bm0 = bmt * BM, bn0 = bnt * BN;
  const unsigned short* A = d.A + (long long)blockIdx.y * d.Ay
      + (long long)blockIdx.z * d.Az + (size_t)bm0 * d.lda;
  const unsigned short* B = d.B + (long long)blockIdx.y * d.By
      + (long long)blockIdx.z * d.Bz + (size_t)bn0 * d.ldb;
  int tid = threadIdx.x, lane = tid & 63, w = tid >> 6;
  int wm = (WGN == 2) ? (w >> 1) : w;
  int wn = (WGN == 2) ? (w & 1) : 0;
  int ln = lane & 15, qd = lane >> 4;

  v4f acc[MT][NT];
#pragma unroll
  for (int i = 0; i < MT; ++i)
#pragma unroll
    for (int j = 0; j < NT; ++j) acc[i][j] = (v4f){0.f, 0.f, 0.f, 0.f};

  int nks = d.K >> 6;
  for (int ks = 0; ks < nks; ++ks) {
    int kof = ks * 64;
#pragma unroll
    for (int it = 0; it < AIT; ++it) {
      int c = it * 256 + tid;
      int row = c >> 3, ch = c & 7;
      async16(A + (size_t)row * d.lda + ((ch ^ (row & 7)) << 3) + kof, As + c * 8);
    }
#pragma unroll
    for (int it = 0; it < BIT; ++it) {
      int c = it * 256 + tid;
      int row = c >> 3, ch = c & 7;
      async16(B + (size_t)row * d.ldb + ((ch ^ (row & 7)) << 3) + kof, Bs + c * 8);
    }
    __syncthreads();
#pragma unroll
    for (int k2 = 0; k2 < 2; ++k2) {
      v8bf af[MT], bfr[NT];
#pragma unroll
      for (int i = 0; i < MT; ++i) {
        int row = wm * MT * 16 + i * 16 + ln;
        af[i] = *(const v8bf*)(As + row * 64 + (((k2*4 + qd) ^ (ln & 7)) << 3));
      }
#pragma unroll
      for (int j = 0; j < NT; ++j) {
        int row = wn * NT * 16 + j * 16 + ln;
        bfr[j] = *(const v8bf*)(Bs + row * 64 + (((k2*4 + qd) ^ (ln & 7)) << 3));
      }
#pragma unroll
      for (int i = 0; i < MT; ++i)
#pragma unroll
        for (int j = 0; j < NT; ++j)
          acc[i][j] = __builtin_amdgcn_mfma_f32_16x16x32_bf16(af[i], bfr[j], acc[i][j], 0, 0, 0);
    }
    __syncthreads();
  }

  size_t obase = (size_t)((long long)blockIdx.y * d.Oy + (long long)blockIdx.z * d.Oz);
#pragma unroll
  for (int i = 0; i < MT; ++i) {
#pragma unroll
    for (int j = 0; j < NT; ++j) {
      int col = bn0 + wn * NT * 16 + j * 16 + ln;
      float bia = d.bias ? d.bias[col] : 0.0f;
#pragma unroll
      for (int r = 0; r < 4; ++r) {
        int row = bm0 + wm * MT * 16 + i * 16 + qd * 4 + r;
        float v = acc[i][j][r] + bia;
        if (d.epi == 2) v = v * sigm(v);
        size_t oi = obase + (size_t)row * d.ldo + col;
        if (d.epi == 0) ((float*)d.out)[oi] = v;
        else ((unsigned short*)d.out)[oi] = f2bf(v);
      }
    }
  }
}

// ---------- flash attention, std MHSA (512 threads) ----------
__global__ __launch_bounds__(512) void flash_attn_kernel(
    const unsigned short* __restrict__ QKVM, const unsigned short* __restrict__ VTB,
    unsigned short* __restrict__ out) {
  __shared__ __align__(16) unsigned short Ks[128*64];
  __shared__ __align__(16) unsigned short Vts[64*128];
  __shared__ __align__(16) unsigned short Pw[8][16*128];
  int h = blockIdx.x, b = blockIdx.y, qt = blockIdx.z;
  int tid = threadIdx.x, lane = tid & 63, w = tid >> 6;
  int ln = lane & 15, qd = lane >> 4;

  const unsigned short* Qbase = QKVM + ((size_t)(b*1024 + qt*128 + w*16))*2560 + h*64;
  v8bf aq[2];
#pragma unroll
  for (int s = 0; s < 2; ++s)
    aq[s] = *(const v8bf*)(Qbase + (size_t)ln*2560 + s*32 + qd*8);

  v4f o_acc[4];
  float l_part[4];
#pragma unroll
  for (int dn = 0; dn < 4; ++dn) o_acc[dn] = (v4f){0.f,0.f,0.f,0.f};
#pragma unroll
  for (int r = 0; r < 4; ++r) l_part[r] = 0.f;

  const unsigned short* Kg = QKVM + 512 + (size_t)(b*1024)*2560 + h*64;
  const unsigned short* Vg = VTB + ((size_t)(b*512) + h*64)*1024;

  for (int kt = 0; kt < 8; ++kt) {
#pragma unroll
    for (int it = 0; it < 2; ++it) {
      int c = it*512 + tid;
      async16(Kg + (size_t)(kt*128 + (c >> 3))*2560 + (((c & 7) ^ ((c >> 3) & 7)) << 3),
              Ks + c*8);
    }
#pragma unroll
    for (int it = 0; it < 2; ++it) {
      int c = it*512 + tid;
      async16(Vg + (size_t)(c >> 4)*1024 + kt*128 + ((((c & 15) ^ ((c >> 4) & 7))) << 3),
              Vts + c*8);
    }
    __syncthreads();

    v4f sc[8];
#pragma unroll
    for (int n = 0; n < 8; ++n) {
      v4f a = (v4f){0.f,0.f,0.f,0.f};
#pragma unroll
      for (int s = 0; s < 2; ++s) {
        v8bf kb = *(const v8bf*)(Ks + (n*16 + ln)*64 + (((s*4 + qd) ^ (ln & 7)) << 3));
        a = __builtin_amdgcn_mfma_f32_16x16x32_bf16(aq[s], kb, a, 0, 0, 0);
      }
      sc[n] = a;
    }
#pragma unroll
    for (int r = 0; r < 4; ++r) {
      int row7 = (qd*4 + r) & 7;
      float acc_l = 0.f;
#pragma unroll
      for (int n = 0; n < 8; ++n) {
        float p = exp2f(sc[n][r]);
        acc_l += p;
        Pw[w][(qd*4 + r)*128 + (((n*2 + (ln >> 3)) ^ row7) << 3) + (ln & 7)] = f2bf_trunc(p);
      }
      l_part[r] += acc_l;
    }
#pragma unroll
    for (int dn = 0; dn < 4; ++dn) {
      v4f a = o_acc[dn];
#pragma unroll
      for (int ks2 = 0; ks2 < 4; ++ks2) {
        int phys = (((ks2*4 + qd) ^ (ln & 7)) << 3);
        v8bf pf = *(const v8bf*)(&Pw[w][ln*128 + phys]);
        v8bf vf = *(const v8bf*)(Vts + (dn*16 + ln)*128 + phys);
        a = __builtin_amdgcn_mfma_f32_16x16x32_bf16(pf, vf, a, 0, 0, 0);
      }
      o_acc[dn] = a;
    }
    __syncthreads();
  }

  unsigned short* ob = out + ((size_t)(b*1024 + qt*128 + w*16))*1024 + h*64;
#pragma unroll
  for (int r = 0; r < 4; ++r) {
    float l = l_part[r];
    l += __shfl_xor(l, 1); l += __shfl_xor(l, 2);
    l += __shfl_xor(l, 4); l += __shfl_xor(l, 8);
    float rinv = 1.0f / l;
#pragma unroll
    for (int dn = 0; dn < 4; ++dn)
      ob[(size_t)(qd*4 + r)*1024 + dn*16 + ln] = f2bf(o_acc[dn][r] * rinv);
  }
}

// ---------- flash attention, multi-scale branches: D=256, single head ----------
__global__ __launch_bounds__(256) void flash_branch_kernel(
    const unsigned short* __restrict__ QKVM, const unsigned short* __restrict__ QM,
    const unsigned short* __restrict__ VMT, unsigned short* __restrict__ out) {
  __shared__ __align__(16) unsigned short Ks[64*256];
  __shared__ __align__(16) unsigned short Vts[256*64];
  __shared__ __align__(16) unsigned short Pw[4][16*64];
  int bb = blockIdx.x, b = bb >> 1, br = bb & 1;
  int qt = blockIdx.z;
  int tid = threadIdx.x, lane = tid & 63, w = tid >> 6;
  int ln = lane & 15, qd = lane >> 4;

  const unsigned short* Qb = QM + ((size_t)(b*1024 + qt*64 + w*16))*512 + br*256;
  v8bf aq[8];
#pragma unroll
  for (int s = 0; s < 8; ++s)
    aq[s] = *(const v8bf*)(Qb + (size_t)ln*512 + s*32 + qd*8);

  v4f o_acc[16];
  float l_part[4];
#pragma unroll
  for (int dn = 0; dn < 16; ++dn) o_acc[dn] = (v4f){0.f,0.f,0.f,0.f};
#pragma unroll
  for (int r = 0; r < 4; ++r) l_part[r] = 0.f;

  const unsigned short* Kg = QKVM + 1536 + br*256 + (size_t)(b*1024)*2560;
  const unsigned short* Vg = VMT + ((size_t)(b*512) + br*256)*1024;

  for (int kt = 0; kt < 16; ++kt) {
#pragma unroll
    for (int it = 0; it < 8; ++it) {
      int c = it*256 + tid;
      int row = c >> 5, ch = c & 31;
      async16(Kg + (size_t)(kt*64 + row)*2560 + ((ch ^ (row & 7)) << 3), Ks + c*8);
    }
#pragma unroll
    for (int it = 0; it < 8; ++it) {
      int c = it*256 + tid;
      int row = c >> 3, ch = c & 7;
      async16(Vg + (size_t)row*1024 + kt*64 + ((ch ^ (row & 7)) << 3), Vts + c*8);
    }
    __syncthreads();

    v4f sc[4];
#pragma unroll
    for (int n = 0; n < 4; ++n) {
      v4f a = (v4f){0.f,0.f,0.f,0.f};
      int krow = n*16 + ln;
#pragma unroll
      for (int s = 0; s < 8; ++s) {
        v8bf kb = *(const v8bf*)(Ks + krow*256 + (((s*4 + qd) ^ (krow & 7)) << 3));
        a = __builtin_amdgcn_mfma_f32_16x16x32_bf16(aq[s], kb, a, 0, 0, 0);
      }
      sc[n] = a;
    }
#pragma unroll
    for (int r = 0; r < 4; ++r) {
      int row7 = (qd*4 + r) & 7;
      float acc_l = 0.f;
#pragma unroll
      for (int n = 0; n < 4; ++n) {
        float p = exp2f(sc[n][r]);
        acc_l += p;
        Pw[w][(qd*4 + r)*64 + (((n*2 + (ln >> 3)) ^ row7) << 3) + (ln & 7)] = f2bf_trunc(p);
      }
      l_part[r] += acc_l;
    }
#pragma unroll
    for (int dn = 0; dn < 16; ++dn) {
      v4f a = o_acc[dn];
#pragma unroll
      for (int ks2 = 0; ks2 < 2; ++ks2) {
        int phys = (((ks2*4 + qd) ^ (ln & 7)) << 3);
        v8bf pf = *(const v8bf*)(&Pw[w][ln*64 + phys]);
        v8bf vf = *(const v8bf*)(Vts + (dn*16 + ln)*64 + phys);
        a = __builtin_amdgcn_mfma_f32_16x16x32_bf16(pf, vf, a, 0, 0, 0);
      }
      o_acc[dn] = a;
    }
    __syncthreads();
  }

  unsigned short* ob = out + ((size_t)(b*1024 + qt*64 + w*16))*1024 + 512 + br*256;
#pragma unroll
  for (int r = 0; r < 4; ++r) {
    float l = l_part[r];
    l += __shfl_xor(l, 1); l += __shfl_xor(l, 2);
    l += __shfl_xor(l, 4); l += __shfl_xor(l, 8);
    float rinv = 1.0f / l;
#pragma unroll
    for (int dn = 0; dn < 16; ++dn)
      ob[(size_t)(qd*4 + r)*1024 + dn*16 + ln] = f2bf(o_acc[dn][r] * rinv);
  }
}

// ---------- stats over (B,S,C) bf16 per (b,group) ----------
__global__ __launch_bounds__(256) void gn_stats_bf16_kernel(
    const unsigned short* __restrict__ t, float* __restrict__ stats) {
  int b = blockIdx.x >> 5, grp = blockIdx.x & 31;
  float s = 0.f, s2 = 0.f;
#pragma unroll
  for (int j = 0; j < 4; ++j) {
    int sI = threadIdx.x + j*256;
    const unsigned short* p = t + ((size_t)(b*1024 + sI))*512 + grp*16;
    uint4 a = *(const uint4*)p, c2 = *(const uint4*)(p + 8);
    unsigned int ww[8] = {a.x,a.y,a.z,a.w,c2.x,c2.y,c2.z,c2.w};
#pragma unroll
    for (int k = 0; k < 8; ++k) {
      float lo = bf2f((unsigned short)(ww[k] & 0xffff));
      float hi = bf2f((unsigned short)(ww[k] >> 16));
      s += lo + hi; s2 += lo*lo + hi*hi;
    }
  }
#pragma unroll
  for (int o = 32; o; o >>= 1) { s += __shfl_xor(s, o); s2 += __shfl_xor(s2, o); }
  __shared__ float rs[4], rs2[4];
  int w = threadIdx.x >> 6;
  if ((threadIdx.x & 63) == 0) { rs[w] = s; rs2[w] = s2; }
  __syncthreads();
  if (threadIdx.x == 0) {
    float ts = rs[0]+rs[1]+rs[2]+rs[3], ts2 = rs2[0]+rs2[1]+rs2[2]+rs2[3];
    float mu = ts * (1.0f/16384.0f);
    float var = ts2 * (1.0f/16384.0f) - mu*mu;
    stats[(b*32+grp)*2] = mu; stats[(b*32+grp)*2+1] = rsqrtf(var + 1e-6f);
  }
}

// ---------- GN(post) + residual ----------
__global__ __launch_bounds__(256) void final_out_kernel(
    const unsigned short* __restrict__ fin, const float* __restrict__ stats,
    const float* __restrict__ g, const float* __restrict__ be,
    const float* __restrict__ x, float* __restrict__ out) {
  __shared__ float t[64][65];
  int s0 = blockIdx.x * 64, c0 = blockIdx.y * 64, b = blockIdx.z;
  int tx = threadIdx.x & 63, ty = threadIdx.x >> 6;
#pragma unroll
  for (int i = 0; i < 16; ++i) {
    int s = ty + i*4;
    t[s][tx] = bf2f(fin[((size_t)(b*1024 + s0 + s))*512 + c0 + tx]);
  }
  __syncthreads();
#pragma unroll
  for (int i = 0; i < 16; ++i) {
    int c = ty + i*4;
    int cc = c0 + c, grp = cc >> 4;
    float mu = stats[(b*32+grp)*2], rstd = stats[(b*32+grp)*2+1];
    float gg = g[cc], bb = be[cc];
    size_t oi = ((size_t)(b*512 + cc))*1024 + s0 + tx;
    out[oi] = (t[tx][c] - mu)*rstd*gg + bb + x[oi];
  }
}

// =====================================================================
static void launch_gemm128(hipStream_t st, const unsigned short* A, const unsigned short* B,
                           void* out, const float* bias,
                           int M, int N, int K, int lda, int ldb, int ldo, int epi,
                           long long Ay, long long Az, long long By, long long Bz,
                           long long Oy, long long Oz, int gy, int gz) {
  GemmDesc d{A, B, out, bias, M, N, K, lda, ldb, ldo, epi, Ay, Az, By, Bz, Oy, Oz};
  gemm_tile_kernel<128,128><<<dim3((M/128)*(N/128), gy, gz), dim3(256), 0, st>>>(d);
}
static void launch_gemm64(hipStream_t st, const unsigned short* A, const unsigned short* B,
                          void* out, const float* bias,
                          int M, int N, int K, int lda, int ldb, int ldo, int epi) {
  GemmDesc d{A, B, out, bias, M, N, K, lda, ldb, ldo, epi, 0,0,0,0,0,0};
  gemm_tile_kernel<128,64><<<dim3((M/128)*(N/64), 1, 1), dim3(256), 0, st>>>(d);
}

extern "C" void kernel_launch(void* const* d_in, const int* in_sizes, int n_in,
                              void* d_out, int out_size, void* d_ws, size_t ws_size,
                              hipStream_t stream) {
  const float* x      = (const float*)d_in[0];
  const float* pre_g  = (const float*)d_in[1];
  const float* pre_b  = (const float*)d_in[2];
  const float* norm_g = (const float*)d_in[3];
  const float* norm_b = (const float*)d_in[4];
  const float* post_g = (const float*)d_in[5];
  const float* post_b = (const float*)d_in[6];
  const float* pos    = (const float*)d_in[7];
  const float* sa_b1  = (const float*)d_in[9];
  const float* sa_b2  = (const float*)d_in[11];
  const float* sa_w3  = (const float*)d_in[12];
  const float* sa_b3  = (const float*)d_in[13];
  const float* ff_b1  = (const float*)d_in[24];
  const float* ff_b2  = (const float*)d_in[26];
  const float* out_w  = (const float*)d_in[27];
  const float* out_b  = (const float*)d_in[28];
  float* outp = (float*)d_out;

  char* ws = (char*)d_ws;
  size_t off = 0;
  auto alloc = [&](size_t bytes) -> void* {
    void* p = ws + off; off += (bytes + 255) & ~(size_t)255; return p;
  };
  float* STATS = (float*)alloc(4096);
  float* BC    = (float*)alloc(2048);
  unsigned short* HSB  = (unsigned short*)alloc(8388608);
  unsigned short* A1   = (unsigned short*)alloc(1048576);
  unsigned short* IM2  = (unsigned short*)alloc(9437184);
  unsigned short* A2   = (unsigned short*)alloc(1048576);
  unsigned short* SHB  = (unsigned short*)alloc(8388608);
  unsigned short* MSHB = (unsigned short*)alloc(8388608);
  unsigned short* WBF  = (unsigned short*)alloc(6291456);
  unsigned short* WCOMB= (unsigned short*)alloc(524288);
  unsigned short* QKVM = (unsigned short*)alloc(41943040);
  unsigned short* QM   = (unsigned short*)alloc(8388608);
  unsigned short* VTB  = (unsigned short*)alloc(8388608);
  unsigned short* VMT  = (unsigned short*)alloc(8388608);
  unsigned short* COMB = (unsigned short*)alloc(16777216);
  unsigned short* FFMID= (unsigned short*)alloc(8388608);
  unsigned short* FINALB=(unsigned short*)alloc(8388608);

  const int OQKVM=0, OQM=1310720, OFF1=1572864, OFF2T=2097152,
            OOW=2359296, OW1=2621440, OW2R=2654208;

  // 1) GN(pre)+pos -> HSB + GN(norm) stats
  gn_pre_kernel<<<dim3(256), dim3(256), 0, stream>>>(x, pre_g, pre_b, pos, HSB, STATS);
  // 2) weights -> bf16 (log2e folded into all attention Q weights)
  {
    WCvtArgs a;
    const float LG2E = 1.4426950408889634f;
    const int   srcIdx[15] = {14,15,16, 18,21,19,22, 17,20, 23,27, 8, 0, 10, 25};
    const int   dofs[15]   = {0, 262144, 524288,
                              786432, 917504, 1048576, 1179648,
                              OQM, OQM+131072,
                              OFF1, OOW, OW1, 0, OW2R, OFF2T};
    const int   ns[15]     = {262144,262144,262144, 131072,131072,131072,131072,
                              131072,131072, 524288,262144, 32768, 0, 36864, 262144};
    const float sc[15]     = {0.125f*LG2E,1.f,1.f, 1.f,1.f,1.f,1.f,
                              0.0625f*LG2E,0.0625f*LG2E, 1.f,1.f, 1.f, 0.f, 1.f, 1.f};
    for (int i = 0; i < 15; ++i) { a.w[i].src = (const float*)d_in[srcIdx[i]]; a.w[i].dstOff = dofs[i]; a.w[i].n = ns[i]; a.w[i].scale = sc[i]; }
    wconvert_kernel<<<dim3(2048, 15), dim3(256), 0, stream>>>(a, WBF);
  }
  // 2b) fold FF2+OW
  {
    GemmDesc d{WBF+OOW, WBF+OFF2T, WCOMB, nullptr, 512, 512, 512, 512, 512, 512, 1, 0,0,0,0,0,0};
    gemm_tile_kernel<128,128><<<dim3(16, 1, 1), dim3(256), 0, stream>>>(d);
  }
  bias_fold_kernel<<<dim3(2), dim3(256), 0, stream>>>(out_w, ff_b2, out_b, BC);
  // 3) spatial gate chain
  launch_gemm64(stream, HSB, WBF+OW1,  A1, sa_b1, 8192, 64, 512, 512, 512, 64, 2);
  im2col_kernel<<<dim3(1024), dim3(256), 0, stream>>>(A1, IM2);
  launch_gemm64(stream, IM2, WBF+OW2R, A2, sa_b2, 8192, 64, 576, 576, 576, 64, 2);
  // 4) gate + norm
  gate_norm_kernel<<<dim3(256, 8), dim3(256), 0, stream>>>(HSB, A2, sa_w3, sa_b3, STATS, norm_g, norm_b, SHB, MSHB);

  // 5) projections
  launch_gemm128(stream, SHB,  WBF+OQKVM, QKVM, nullptr, 8192, 2560, 512, 512, 512, 2560, 1, 0,0,0,0,0,0, 1,1);
  launch_gemm64(stream, MSHB, WBF+OQM,   QM,   nullptr, 8192, 512,  512, 512, 512, 512,  1);

  // 6) V transposes
  transpose2_kernel<<<dim3(16, 8, 16), dim3(256), 0, stream>>>(QKVM, VTB, VMT);

  // 7) std MHSA flash -> COMB[:, 0:512]
  flash_attn_kernel<<<dim3(8, 8, 8), dim3(512), 0, stream>>>(QKVM, VTB, COMB);

  // 8) branch flash -> COMB[:, 512:1024]
  flash_branch_kernel<<<dim3(16, 1, 16), dim3(256), 0, stream>>>(QKVM, QM, VMT, COMB);

  // 9) FF (folded FF2+OW)
  launch_gemm64(stream, COMB,  WBF+OFF1, FFMID,  ff_b1, 8192, 512, 1024, 1024, 1024, 512, 2);
  launch_gemm64(stream, FFMID, WCOMB,    FINALB, BC,    8192, 512, 512,  512,  512,  512, 1);

  // 10) GN(post) + residual
  gn_stats_bf16_kernel<<<dim3(256), dim3(256), 0, stream>>>(FINALB, STATS);
  final_out_kernel<<<dim3(16, 8, 8), dim3(256), 0, stream>>>(FINALB, STATS, post_g, post_b, x, outp);

  (void)in_sizes; (void)n_in; (void)out_size; (void)ws_size;
}